// Round 1
// baseline (119.643 us; speedup 1.0000x reference)
//
#include <hip/hip_runtime.h>
#include <math.h>

#define N_SAMPLES 131072
#define NUM_CLASSES 128
#define NB 64                 // bins (width 1/4 over s in [-14, 2])
#define MAX_FPR 0.7f          // 1 - RECALL_THRESHOLD
#define NBLK 512              // fused grid: 2 blocks/CU
#define ROWS_PER_BLK 256      // max per-bin count/block = 256 -> u16-safe
#define HP 33                 // class row pitch in LDS u32 words (32 + 1 pad)

typedef unsigned int u32;

// bin(x; L) = floor((x - L + 14) * 4) clamped to [0,63]. Identical expression
// for the positive and the all histogram (same kernel, same registers).
__device__ __forceinline__ int bin_of(float x, float off /* (14-lse)*4 */) {
    int b = (int)__fmaf_rn(x, 4.0f, off);
    return min(max(b, 0), NB - 1);
}

// ---------------------------------------------------------------------------
// Single fused kernel. Main loop is the proven r10 body (NB=64, two LDS
// hists, 34 KB LDS -> 2 blocks/CU, 256 rows/block, 16 lanes/row, 8 cols/lane,
// 2-deep pipeline, 4 passes). NEW vs previous version:
//   - Instead of dumping 16.8 MB of per-block partials to HBM and re-reading
//     them in a second kernel, each block merges its LDS hists into ONE
//     global 64 KB histogram via device atomicAdd with zero-skip (per-block
//     hists are sparse: ~24/64 'all' bins, ~2% 'pos' bins nonzero -> ~1.7M
//     atomics total over 16K addresses; <=512 serialized adds/address).
//   - Last-ticket block (threadfence -> atomicAdd(doneCtr) -> agent-scope
//     loads; same pattern the old pauc_reduce used) computes all 128 class
//     pAUCs (one class per 64-lane wave, 8 rounds over 16 waves) and the
//     final scalar, replicating the old reduction's exact op order so the
//     output stays bit-identical.
// Saves: 16.8 MB write + 16.8 MB read (~5.3 us @6.3 TB/s) + the second
// kernel's launch + its half-idle-grid inefficiency. Costs: one 64 KB
// hipMemsetAsync (hist + doneCtr must be zero; harness poisons d_ws).
// ---------------------------------------------------------------------------
__global__ __launch_bounds__(1024, 8) void fused_kernel(
    const float* __restrict__ pred, const int* __restrict__ tgt,
    u32* __restrict__ gAll,      // [128][64] global 'all' histogram (zeroed)
    u32* __restrict__ gPos,      // [128][64] global 'pos' histogram (zeroed)
    u32* __restrict__ doneCtr,   // zeroed by memset
    float* __restrict__ ceArr,   // [NBLK] plain-stored CE partials (no init)
    float* __restrict__ out)
{
    __shared__ u32 hA[NUM_CLASSES * HP];   // all hist, u16x2  (16.9 KB)
    __shared__ u32 hP[NUM_CLASSES * HP];   // pos hist, u16x2  (16.9 KB)
    __shared__ float wsum[16];
    __shared__ float pauc_s[NUM_CLASSES];
    __shared__ float valid_s[NUM_CLASSES];
    __shared__ u32 tkt;

    const int tid  = threadIdx.x;
    const int w    = tid >> 6;        // wave 0..15
    const int lane = tid & 63;
    const int j    = lane & 15;       // lane within row
    const int rs   = lane >> 4;       // row sub-index 0..3

    for (int i = tid; i < NUM_CLASSES * HP; i += 1024) { hA[i] = 0u; hP[i] = 0u; }
    __syncthreads();

    const int rowBase = blockIdx.x * ROWS_PER_BLK + w * 4 + rs;
    float acc_lse = 0.0f, acc_xt = 0.0f, acc_sx = 0.0f;

    // 2-deep pipeline over 4 passes (row stride 64 per pass)
    const float* r0p = pred + (size_t)rowBase * 128;
    float4 a0 = *(const float4*)(r0p + j * 4);
    float4 a1 = *(const float4*)(r0p + 64 + j * 4);
    int    ta = tgt[rowBase];
    const float* r1p = r0p + (size_t)64 * 128;
    float4 c0 = *(const float4*)(r1p + j * 4);
    float4 c1 = *(const float4*)(r1p + 64 + j * 4);
    int    tb = tgt[rowBase + 64];

    #pragma unroll
    for (int p = 0; p < 4; p++) {
        float4 n0, n1; int tn = 0;
        if (p < 2) {
            const float* rn = pred + (size_t)(rowBase + (p + 2) * 64) * 128;
            n0 = *(const float4*)(rn + j * 4);
            n1 = *(const float4*)(rn + 64 + j * 4);
            tn = tgt[rowBase + (p + 2) * 64];
        }

        float e = __expf(a0.x) + __expf(a0.y) + __expf(a0.z) + __expf(a0.w)
                + __expf(a1.x) + __expf(a1.y) + __expf(a1.z) + __expf(a1.w);
        #pragma unroll
        for (int o = 1; o < 16; o <<= 1) e += __shfl_xor(e, o);
        const float lse = __logf(e);
        const float off = (14.0f - lse) * 4.0f;

        const float xv[8] = {a0.x, a0.y, a0.z, a0.w, a1.x, a1.y, a1.z, a1.w};
        #pragma unroll
        for (int q = 0; q < 8; q++) {
            const int c = (q < 4) ? (j * 4 + q) : (64 + j * 4 + (q - 4));
            const int b = bin_of(xv[q], off);
            const int word = ((b >> 1) + j) & 31;       // swizzle: 16 banks
            atomicAdd(&hA[c * HP + word], (b & 1) ? 65536u : 1u);
        }

        acc_sx  += (xv[0] + xv[1] + xv[2] + xv[3])
                 + (xv[4] + xv[5] + xv[6] + xv[7]);
        acc_lse += lse * 0.0625f;     // 16 lanes/row each add lse/16

        {   // exactly one of the row's 16 lanes owns the target column
            const int t = ta;
            float xt; bool hit = false;
            if ((t >> 2) == j)                        { xt = xv[t & 3];       hit = true; }
            else if (t >= 64 && ((t - 64) >> 2) == j) { xt = xv[4 + (t & 3)]; hit = true; }
            if (hit) {
                acc_xt += xt;
                const int bp = bin_of(xt, off);
                atomicAdd(&hP[t * HP + (((bp >> 1) + j) & 31)],
                          (bp & 1) ? 65536u : 1u);
            }
        }

        a0 = c0; a1 = c1; ta = tb;
        c0 = n0; c1 = n1; tb = tn;
    }

    // CE partial: sum(lse) - 0.9*sum(x_t) - (0.1/128)*sum(x)
    float ce = acc_lse - 0.9f * acc_xt - (0.1f / 128.0f) * acc_sx;
    #pragma unroll
    for (int o = 32; o; o >>= 1) ce += __shfl_xor(ce, o);
    if (lane == 0) wsum[w] = ce;
    __syncthreads();                   // all LDS hist atomics done here too
    if (tid == 0) {
        float s = 0.0f;
        #pragma unroll
        for (int i = 0; i < 16; i++) s += wsum[i];
        ceArr[blockIdx.x] = s;         // plain store, no init needed
    }

    // ------------------------------------------------------------------
    // Zero-skip atomic merge into the global 64 KB histogram.
    // i = c*64 + b, linear. LDS read un-swizzles: row-lane group for class
    // c was j = (c>>2)&15. Lanes of one wave cover one class -> 32 distinct
    // words, HP=33 pitch -> conflict-free; even/odd b share a word
    // (same-address broadcast, free).
    // ------------------------------------------------------------------
    for (int i = tid; i < NUM_CLASSES * NB; i += 1024) {
        const int c  = i >> 6, b = i & 63;
        const int sw = c * HP + (((b >> 1) + ((c >> 2) & 15)) & 31);
        const u32 wa = hA[sw];
        const u32 wp = hP[sw];
        const u32 ca = (b & 1) ? (wa >> 16) : (wa & 0xffffu);
        const u32 cp = (b & 1) ? (wp >> 16) : (wp & 0xffffu);
        if (ca) atomicAdd(&gAll[i], ca);
        if (cp) atomicAdd(&gPos[i], cp);
    }

    // ------------------------------------------------------------------
    // Last-ticket block finalizes. Barrier drains this block's atomics
    // (vmcnt 0 before s_barrier); release fence before the ticket makes
    // them + ceArr visible; agent-scope loads on the reader side bypass
    // non-coherent L1/L2 (same proven pattern as the old pauc_reduce).
    // ------------------------------------------------------------------
    __syncthreads();
    if (tid == 0) { __threadfence(); tkt = atomicAdd(doneCtr, 1u); }
    __syncthreads();
    if (tkt != NBLK - 1u) return;

    // 16 waves x 8 rounds = 128 classes; lane l owns DESCENDING bin 63-l.
    for (int r = 0; r < 8; r++) {
        const int k = w * 8 + r;
        const int l = lane;
        const u32 a = __hip_atomic_load(&gAll[k * 64 + 63 - l],
                                        __ATOMIC_RELAXED, __HIP_MEMORY_SCOPE_AGENT);
        const u32 p = __hip_atomic_load(&gPos[k * 64 + 63 - l],
                                        __ATOMIC_RELAXED, __HIP_MEMORY_SCOPE_AGENT);

        u32 ia = a, ip = p;           // inclusive scan (descending order)
        #pragma unroll
        for (int o = 1; o < 64; o <<= 1) {
            const u32 tA = __shfl_up(ia, o);
            const u32 tP = __shfl_up(ip, o);
            if (l >= o) { ia += tA; ip += tP; }
        }
        const u32 P = __shfl(ip, 63);
        const u32 T = __shfl(ia, 63);
        const float Pm = fmaxf((float)P, 1.0f);
        const float Fm = fmaxf((float)(T - P), 1.0f);

        const int cumA = (int)(ia - a), cumP = (int)(ip - p);  // exclusive
        float contrib = 0.0f;
        const int f = (int)a - (int)p;
        if (f > 0) {
            const float fpr0 = (float)(cumA - cumP) / Fm;
            if (fpr0 < MAX_FPR) {
                const float tpr0 = (float)cumP / Pm;
                const float tpr1 = (float)(cumP + (int)p) / Pm;
                const float fpr1 = (float)(cumA - cumP + f) / Fm;
                if (fpr1 <= MAX_FPR) {
                    contrib = (fpr1 - fpr0) * 0.5f * (tpr0 + tpr1);
                } else {
                    const float tfrac = (MAX_FPR - fpr0) / (fpr1 - fpr0);
                    const float tprc  = tpr0 + tfrac * (tpr1 - tpr0);
                    contrib = (MAX_FPR - fpr0) * 0.5f * (tpr0 + tprc);
                }
            }
        }
        #pragma unroll
        for (int o = 32; o; o >>= 1) contrib += __shfl_xor(contrib, o);
        if (l == 0) {
            pauc_s[k]  = (P > 0u) ? contrib : 0.0f;
            valid_s[k] = (P > 0u) ? 1.0f : 0.0f;
        }
    }
    __syncthreads();

    if (w == 0) {   // replicate old gather order exactly (bitwise-identical)
        float s1 = pauc_s[lane] + pauc_s[lane + 64];
        float s2 = valid_s[lane] + valid_s[lane + 64];
        float s3 = 0.0f;
        #pragma unroll
        for (int i = 0; i < 8; i++)
            s3 += __hip_atomic_load(ceArr + lane + i * 64,
                                    __ATOMIC_RELAXED, __HIP_MEMORY_SCOPE_AGENT);
        #pragma unroll
        for (int o = 32; o; o >>= 1) {
            s1 += __shfl_xor(s1, o);
            s2 += __shfl_xor(s2, o);
            s3 += __shfl_xor(s3, o);
        }
        if (lane == 0) {
            const float cem  = s3 * (1.0f / (float)N_SAMPLES);
            const float pauc = s1 / fmaxf(s2, 1.0f);
            out[0] = 0.5f * cem + 0.5f * (1.0f - pauc * pauc);
        }
    }
}

extern "C" void kernel_launch(void* const* d_in, const int* in_sizes, int n_in,
                              void* d_out, int out_size, void* d_ws, size_t ws_size,
                              hipStream_t stream)
{
    const float* pred = (const float*)d_in[0];
    const int*   tgt  = (const int*)d_in[1];

    char* ws = (char*)d_ws;
    u32*   gAll    = (u32*)ws;                  // 32 KB
    u32*   gPos    = (u32*)(ws + 32768);        // 32 KB
    u32*   doneCtr = (u32*)(ws + 65536);        // 4 B
    float* ceArr   = (float*)(ws + 66560);      // 2 KB, no init needed

    // Zero hist + doneCtr (harness poisons d_ws every iteration).
    // 64 KB memset: latency-bound, ~1-2 us, graph-capturable.
    hipMemsetAsync(ws, 0, 66560, stream);
    fused_kernel<<<NBLK, 1024, 0, stream>>>(pred, tgt, gAll, gPos, doneCtr,
                                            ceArr, (float*)d_out);
}

// Round 4
// 102.915 us; speedup vs baseline: 1.1625x; 1.1625x over previous
//
#include <hip/hip_runtime.h>
#include <math.h>

#define N_SAMPLES 131072
#define NUM_CLASSES 128
#define NB 64                 // bins (width 1/4 over s in [-14, 2])
#define MAX_FPR 0.7f          // 1 - RECALL_THRESHOLD
#define NBLK 512              // fused grid: 2 blocks/CU
#define ROWS_PER_BLK 256      // max per-bin count/block = 256 -> u16-safe
#define HP 33                 // class row pitch in LDS u32 words (32 + 1 pad)
// Partial layout per block: [0..4095] all-hist u16x2 (16 KB),
// [4096..6143] pos-hist u8x4 (8 KB). 24 KB/block -> 12.6 MB total.
#define PART_WORDS 6144

typedef unsigned int u32;

// bin(x; L) = floor((x - L + 14) * 4) clamped to [0,63]. Identical expression
// for the positive and the all histogram (same kernel, same registers).
__device__ __forceinline__ int bin_of(float x, float off /* (14-lse)*4 */) {
    int b = (int)__fmaf_rn(x, 4.0f, off);
    return min(max(b, 0), NB - 1);
}

// ---------------------------------------------------------------------------
// Fused phase 1 — proven r10 body (NB=64, two LDS hists, 34 KB LDS ->
// 2 blocks/CU, 256 rows/block, 16 lanes/row, 8 cols/lane via two coalesced
// float4 loads, 2-deep pipeline, 4 passes). Main loop is BYTE-IDENTICAL to
// the 104.8us round-0 kernel. Round-1 lesson: ~2M device-scope atomics cost
// ~9ns each (op-rate wall) = +18-30us; the streamed partials round-trip
// (~5us) is strictly cheaper. Only change here vs round 0: the pos partial
// is packed u8x4 at WRITEOUT (LDS stays u16x2), shrinking partials
// 16.8 -> 12.6 MB. Per-(block,class,bin) pos counts <= positives of that
// class in 256 rows (Binomial(256,1/128), max ~10) -> u8 safe; min(,255)
// guards catastrophe. NOTHING in d_ws needs pre-zeroing:
//  - partials are fully overwritten (plain stores)
//  - ceArr[block] is a plain store
//  - doneCtr is zeroed here by block 0 (only the NEXT kernel reads it)
// ---------------------------------------------------------------------------
__global__ __launch_bounds__(1024, 8) void fused_kernel(
    const float* __restrict__ pred, const int* __restrict__ tgt,
    u32* __restrict__ part,      // [NBLK][6144]
    float* __restrict__ ceArr,   // [NBLK] plain-stored CE partials
    u32* __restrict__ doneCtr)
{
    __shared__ u32 hA[NUM_CLASSES * HP];   // all hist, u16x2  (16.9 KB)
    __shared__ u32 hP[NUM_CLASSES * HP];   // pos hist, u16x2  (16.9 KB)
    __shared__ float wsum[16];

    const int tid  = threadIdx.x;
    const int w    = tid >> 6;        // wave 0..15
    const int lane = tid & 63;
    const int j    = lane & 15;       // lane within row
    const int rs   = lane >> 4;       // row sub-index 0..3

    for (int i = tid; i < NUM_CLASSES * HP; i += 1024) { hA[i] = 0u; hP[i] = 0u; }
    if (blockIdx.x == 0 && tid == 0) *doneCtr = 0u;
    __syncthreads();

    const int rowBase = blockIdx.x * ROWS_PER_BLK + w * 4 + rs;
    float acc_lse = 0.0f, acc_xt = 0.0f, acc_sx = 0.0f;

    // 2-deep pipeline over 4 passes (row stride 64 per pass)
    const float* r0p = pred + (size_t)rowBase * 128;
    float4 a0 = *(const float4*)(r0p + j * 4);
    float4 a1 = *(const float4*)(r0p + 64 + j * 4);
    int    ta = tgt[rowBase];
    const float* r1p = r0p + (size_t)64 * 128;
    float4 c0 = *(const float4*)(r1p + j * 4);
    float4 c1 = *(const float4*)(r1p + 64 + j * 4);
    int    tb = tgt[rowBase + 64];

    #pragma unroll
    for (int p = 0; p < 4; p++) {
        float4 n0, n1; int tn = 0;
        if (p < 2) {
            const float* rn = pred + (size_t)(rowBase + (p + 2) * 64) * 128;
            n0 = *(const float4*)(rn + j * 4);
            n1 = *(const float4*)(rn + 64 + j * 4);
            tn = tgt[rowBase + (p + 2) * 64];
        }

        float e = __expf(a0.x) + __expf(a0.y) + __expf(a0.z) + __expf(a0.w)
                + __expf(a1.x) + __expf(a1.y) + __expf(a1.z) + __expf(a1.w);
        #pragma unroll
        for (int o = 1; o < 16; o <<= 1) e += __shfl_xor(e, o);
        const float lse = __logf(e);
        const float off = (14.0f - lse) * 4.0f;

        const float xv[8] = {a0.x, a0.y, a0.z, a0.w, a1.x, a1.y, a1.z, a1.w};
        #pragma unroll
        for (int q = 0; q < 8; q++) {
            const int c = (q < 4) ? (j * 4 + q) : (64 + j * 4 + (q - 4));
            const int b = bin_of(xv[q], off);
            const int word = ((b >> 1) + j) & 31;       // swizzle: 16 banks
            atomicAdd(&hA[c * HP + word], (b & 1) ? 65536u : 1u);
        }

        acc_sx  += (xv[0] + xv[1] + xv[2] + xv[3])
                 + (xv[4] + xv[5] + xv[6] + xv[7]);
        acc_lse += lse * 0.0625f;     // 16 lanes/row each add lse/16

        {   // exactly one of the row's 16 lanes owns the target column
            const int t = ta;
            float xt; bool hit = false;
            if ((t >> 2) == j)                        { xt = xv[t & 3];       hit = true; }
            else if (t >= 64 && ((t - 64) >> 2) == j) { xt = xv[4 + (t & 3)]; hit = true; }
            if (hit) {
                acc_xt += xt;
                const int bp = bin_of(xt, off);
                atomicAdd(&hP[t * HP + (((bp >> 1) + j) & 31)],
                          (bp & 1) ? 65536u : 1u);
            }
        }

        a0 = c0; a1 = c1; ta = tb;
        c0 = n0; c1 = n1; tb = tn;
    }

    // CE partial: sum(lse) - 0.9*sum(x_t) - (0.1/128)*sum(x)
    float ce = acc_lse - 0.9f * acc_xt - (0.1f / 128.0f) * acc_sx;
    #pragma unroll
    for (int o = 32; o; o >>= 1) ce += __shfl_xor(ce, o);
    if (lane == 0) wsum[w] = ce;
    __syncthreads();
    if (tid == 0) {
        float s = 0.0f;
        #pragma unroll
        for (int i = 0; i < 16; i++) s += wsum[i];
        ceArr[blockIdx.x] = s;       // plain store, no init needed
    }

    // un-rotating writeout. All-hist: linear i = c*32 + bw, u16x2 unchanged.
    u32* outp = part + (size_t)blockIdx.x * PART_WORDS;
    for (int i = tid; i < 4096; i += 1024) {
        const int c = i >> 5, bw = i & 31;
        const int src = c * HP + ((bw + ((c >> 2) & 15)) & 31);
        outp[i] = hA[src];
    }
    // Pos-hist: pack 4 bins/u32 (u8 each). Word w4 of class c covers bins
    // 4*w4 .. 4*w4+3, i.e. LDS u16x2 words (2*w4 + jc)&31 and (2*w4+1 + jc)&31.
    for (int i = tid; i < 2048; i += 1024) {
        const int c  = i >> 4, w4 = i & 15;
        const int jc = (c >> 2) & 15;
        const u32 lo = hP[c * HP + (((2 * w4)     + jc) & 31)]; // bins 4w4,4w4+1
        const u32 hi = hP[c * HP + (((2 * w4 + 1) + jc) & 31)]; // bins 4w4+2,+3
        const u32 b0 = min(lo & 0xffffu, 255u);
        const u32 b1 = min(lo >> 16,     255u);
        const u32 b2 = min(hi & 0xffffu, 255u);
        const u32 b3 = min(hi >> 16,     255u);
        outp[4096 + i] = b0 | (b1 << 8) | (b2 << 16) | (b3 << 24);
    }
}

// ---------------------------------------------------------------------------
// Reducer + finalize: one block per class, 1024 threads (was 256) for 4x
// the memory-level parallelism on the latency-bound strided partial reads.
// Thread t: word w = t&31 (bins 2w, 2w+1), slice sl = t>>5 covers 16 of the
// 512 partials (coalesced, 8-deep MLP). Pos hist unpacks u8x4: lanes 2k,2k+1
// share pos word w>>1 (broadcast). LDS-atomic merge into 64 u32 bins each,
// then wave 0 (t<64) does the scan + clipped trapezoidal pAUC. Ticket /
// fence / agent-scope-load finalize identical to the verified round-0 code.
// ---------------------------------------------------------------------------
__global__ __launch_bounds__(1024) void pauc_reduce(
    const u32* __restrict__ part, const float* __restrict__ ceArr,
    float* __restrict__ paucArr, float* __restrict__ validArr,
    u32* __restrict__ doneCtr, float* __restrict__ out)
{
    __shared__ u32 aB[NB], pB[NB];

    const int k  = blockIdx.x;
    const int t  = threadIdx.x;
    const int w  = t & 31;            // packed u16x2 word within class row
    const int sl = t >> 5;            // slice of the partials (32 x 16)

    if (t < NB) { aB[t] = 0u; pB[t] = 0u; }
    __syncthreads();

    u32 alo = 0u, ahi = 0u, plo = 0u, phi = 0u;
    const u32* baseA = part + (size_t)(sl * 16) * PART_WORDS + k * 32 + w;
    const u32* baseP = part + (size_t)(sl * 16) * PART_WORDS + 4096 + k * 16 + (w >> 1);
    const int  psh   = 16 * (w & 1);  // byte pair within the u8x4 pos word
    #pragma unroll 8
    for (int b = 0; b < 16; b++) {
        const u32 qa = baseA[(size_t)b * PART_WORDS];
        const u32 qp = baseP[(size_t)b * PART_WORDS];
        alo += qa & 0xffffu;            ahi += qa >> 16;
        plo += (qp >> psh) & 0xffu;     phi += (qp >> (psh + 8)) & 0xffu;
    }
    atomicAdd(&aB[2 * w], alo); atomicAdd(&aB[2 * w + 1], ahi);
    atomicAdd(&pB[2 * w], plo); atomicAdd(&pB[2 * w + 1], phi);
    __syncthreads();

    if (t < 64) {
        const int l = t;
        const u32 a = aB[63 - l];     // lane l owns DESCENDING bin 63-l
        const u32 p = pB[63 - l];

        u32 ia = a, ip = p;           // inclusive scan (descending order)
        #pragma unroll
        for (int o = 1; o < 64; o <<= 1) {
            const u32 tA = __shfl_up(ia, o);
            const u32 tP = __shfl_up(ip, o);
            if (l >= o) { ia += tA; ip += tP; }
        }
        const u32 P = __shfl(ip, 63);
        const u32 T = __shfl(ia, 63);
        const float Pm = fmaxf((float)P, 1.0f);
        const float Fm = fmaxf((float)(T - P), 1.0f);

        const int cumA = (int)(ia - a), cumP = (int)(ip - p);  // exclusive
        float contrib = 0.0f;
        const int f = (int)a - (int)p;
        if (f > 0) {
            const float fpr0 = (float)(cumA - cumP) / Fm;
            if (fpr0 < MAX_FPR) {
                const float tpr0 = (float)cumP / Pm;
                const float tpr1 = (float)(cumP + (int)p) / Pm;
                const float fpr1 = (float)(cumA - cumP + f) / Fm;
                if (fpr1 <= MAX_FPR) {
                    contrib = (fpr1 - fpr0) * 0.5f * (tpr0 + tpr1);
                } else {
                    const float tfrac = (MAX_FPR - fpr0) / (fpr1 - fpr0);
                    const float tprc  = tpr0 + tfrac * (tpr1 - tpr0);
                    contrib = (MAX_FPR - fpr0) * 0.5f * (tpr0 + tprc);
                }
            }
        }
        #pragma unroll
        for (int o = 32; o; o >>= 1) contrib += __shfl_xor(contrib, o);

        int isLast = 0;
        if (l == 0) {
            paucArr[k]  = (P > 0u) ? contrib : 0.0f;   // plain stores
            validArr[k] = (P > 0u) ? 1.0f : 0.0f;
            __threadfence();
            const u32 tk = atomicAdd(doneCtr, 1u);
            isLast = (tk == NUM_CLASSES - 1);
        }
        isLast = __shfl(isLast, 0);

        if (isLast) {   // all 64 lanes gather + reduce
            float s1 = 0.0f, s2 = 0.0f, s3 = 0.0f;
            #pragma unroll
            for (int i = l; i < NUM_CLASSES; i += 64) {
                s1 += __hip_atomic_load(paucArr + i,  __ATOMIC_RELAXED,
                                        __HIP_MEMORY_SCOPE_AGENT);
                s2 += __hip_atomic_load(validArr + i, __ATOMIC_RELAXED,
                                        __HIP_MEMORY_SCOPE_AGENT);
            }
            #pragma unroll
            for (int i = l; i < NBLK; i += 64) s3 += ceArr[i];  // prev kernel
            #pragma unroll
            for (int o = 32; o; o >>= 1) {
                s1 += __shfl_xor(s1, o);
                s2 += __shfl_xor(s2, o);
                s3 += __shfl_xor(s3, o);
            }
            if (l == 0) {
                const float cem  = s3 * (1.0f / (float)N_SAMPLES);
                const float pauc = s1 / fmaxf(s2, 1.0f);
                out[0] = 0.5f * cem + 0.5f * (1.0f - pauc * pauc);
            }
        }
    }
}

extern "C" void kernel_launch(void* const* d_in, const int* in_sizes, int n_in,
                              void* d_out, int out_size, void* d_ws, size_t ws_size,
                              hipStream_t stream)
{
    const float* pred = (const float*)d_in[0];
    const int*   tgt  = (const int*)d_in[1];

    char* ws = (char*)d_ws;
    u32*   part    = (u32*)ws;                          // 12.58 MB partials
    float* ceArr   = (float*)(ws + 12582912);           // 2 KB
    float* paucArr = (float*)(ws + 12582912 + 2048);    // 512 B
    float* validArr= (float*)(ws + 12582912 + 2560);    // 512 B
    u32*   doneCtr = (u32*)  (ws + 12582912 + 3072);    // 4 B

    // NO memset: nothing in d_ws requires initialization (see kernel notes).
    fused_kernel<<<NBLK, 1024, 0, stream>>>(pred, tgt, part, ceArr, doneCtr);
    pauc_reduce<<<NUM_CLASSES, 1024, 0, stream>>>(part, ceArr, paucArr, validArr,
                                                  doneCtr, (float*)d_out);
}